// Round 2
// baseline (1016.846 us; speedup 1.0000x reference)
//
#include <hip/hip_runtime.h>

typedef unsigned short ushort_t;
typedef unsigned int uint_t;

// ---------------------------------------------------------------------------
// GCN 3-layer forward.  N=50000, E=800000, D=H=128, C=40.
// Round 19: keep R18's agg+gemm fusion (kills bufB fp32 round-trip) but fix
// the concurrency failure: BM 64 -> 16.  Grid 782 -> 3125 blocks (12/CU
// queued), LDS 49.7 -> 24.7 KB (6 blocks/CU resident = 24 waves), each wave
// aggregates only 4 rows serially.  Phase B remapped to 2 rows x 4 cols per
// thread: sA reads are wave-uniform (LDS broadcast), sW float4 2-way (free).
// W2 re-staged per block = 64KB x 3125 from L2 (~200MB L2, ~6us) — cheap.
// Numerics identical to R17/R18 (h stays fp32 in LDS).
// Chain: memset -> k_l1(gemm1 ∪ deg) -> scan -> fill -> ag128(agg1+gemm2)
//        -> ag40(agg2+gemm3) -> agg40.   (7 dispatches)
// ws layout: [deg:N int][partials:nb u64][rowptr:N+1][cursor:N][dinv:N f32]
//            [csr:E int2][bufA:N*128 bf16][bufC:N*128 bf16][bufD:N*64 bf16]
// ---------------------------------------------------------------------------

// Single-dispatch scan, wave-parallel decoupled lookback (R16).
__global__ __launch_bounds__(256) void k_scan(
        const int* __restrict__ deg, unsigned long long* __restrict__ partials,
        int* __restrict__ rowptr, int* __restrict__ cursor,
        float* __restrict__ dinv, int n) {
    __shared__ int s[256];
    __shared__ int sprefix;
    const int b = blockIdx.x, t = threadIdx.x;
    const int i = b * 256 + t;
    int v = (i < n) ? deg[i] : 0;
    s[t] = v;
    __syncthreads();
    for (int off = 1; off < 256; off <<= 1) {
        int u = (t >= off) ? s[t - off] : 0;
        __syncthreads();
        s[t] += u;
        __syncthreads();
    }
    if (t == 0) {
        __hip_atomic_store(&partials[b],
                ((unsigned long long)s[255] << 2) | 1ull,
                __ATOMIC_RELEASE, __HIP_MEMORY_SCOPE_AGENT);
        if (b == 0) {
            __hip_atomic_store(&partials[0],
                    ((unsigned long long)s[255] << 2) | 2ull,
                    __ATOMIC_RELEASE, __HIP_MEMORY_SCOPE_AGENT);
            sprefix = 0;
        }
    }
    if (b > 0 && t < 64) {
        int acc = 0;
        int k = b - 1;
        for (;;) {
            int idx = k - t;
            unsigned long long p;
            unsigned st;
            do {
                if (idx >= 0) {
                    p = __hip_atomic_load(&partials[idx],
                            __ATOMIC_ACQUIRE, __HIP_MEMORY_SCOPE_AGENT);
                } else {
                    p = 2ull;
                }
                st = (unsigned)(p & 3ull);
            } while (st == 0);
            unsigned long long bal = __ballot(st == 2);
            int L = (bal != 0) ? (__ffsll((unsigned long long)bal) - 1) : 64;
            int val = (int)(p >> 2);
            int contrib = (t <= L) ? val : 0;
            #pragma unroll
            for (int o = 32; o > 0; o >>= 1) contrib += __shfl_down(contrib, o);
            if (t == 0) acc += contrib;
            if (L < 64) break;
            k -= 64;
        }
        if (t == 0) {
            __hip_atomic_store(&partials[b],
                    (((unsigned long long)(acc + s[255])) << 2) | 2ull,
                    __ATOMIC_RELEASE, __HIP_MEMORY_SCOPE_AGENT);
            sprefix = acc;
        }
    }
    __syncthreads();
    if (i < n) {
        int ex = sprefix + s[t] - v;
        rowptr[i] = ex;
        cursor[i] = ex;
        dinv[i] = rsqrtf((float)(v + 1));
        if (i == n - 1) rowptr[n] = ex + v;
    }
}

// XCD-partitioned scatter (R12).
__global__ __launch_bounds__(256) void k_fill(const int* __restrict__ ei,
                                              int* __restrict__ cursor,
                                              const float* __restrict__ dinv,
                                              int2* __restrict__ csr, int E, int n) {
    const int xcd = blockIdx.x & 7;
    const int e = (blockIdx.x >> 3) * 256 + threadIdx.x;
    if (e >= E) return;
    int d = ei[E + e];
    const int lo = (int)(((long long)xcd * n) >> 3);
    const int hi = (int)(((long long)(xcd + 1) * n) >> 3);
    if (d < lo || d >= hi) return;
    int s = ei[e];
    int pos = atomicAdd(&cursor[d], 1);
    int2 p;
    p.x = s;
    p.y = __float_as_int(dinv[s] * dinv[d]);
    csr[pos] = p;
}

__device__ __forceinline__ ushort_t f2bf_rne(float f) {
    uint_t u = __float_as_uint(f);
    u += 0x7fffu + ((u >> 16) & 1u);
    return (ushort_t)(u >> 16);
}
__device__ __forceinline__ float bflo(uint_t u) {
    return __uint_as_float(u << 16);
}
__device__ __forceinline__ float bfhi(uint_t u) {
    return __uint_as_float(u & 0xffff0000u);
}

// ---- UNION: blocks [0,gemmGrid) = Ybf16[N,128]=X@W1 (BM=128, 8x8 utile);
//      blocks [gemmGrid, ...) = deg_count (1 edge/thread).  Independent work.
__global__ __launch_bounds__(256) void k_l1(const float* __restrict__ X,
                                            const float* __restrict__ W,
                                            ushort_t* __restrict__ Y, int N,
                                            const int* __restrict__ ei,
                                            int* __restrict__ deg, int E,
                                            int gemmGrid) {
    __shared__ float sX[32][132];
    __shared__ float sW[32][128];
    if ((int)blockIdx.x >= gemmGrid) {
        int e = ((int)blockIdx.x - gemmGrid) * 256 + threadIdx.x;
        if (e < E) atomicAdd(&deg[ei[E + e]], 1);   // dst = ei[E+e]
        return;
    }
    const int tid = threadIdx.x;
    const int bm = blockIdx.x * 128;
    const int m0 = (tid >> 4) * 8;
    const int c4 = (tid & 15) * 4;
    const int xf = tid & 7;
    float acc[8][8] = {};
    for (int k0 = 0; k0 < 128; k0 += 32) {
        #pragma unroll
        for (int it = 0; it < 4; ++it) {
            int i = tid + it * 256;
            int row = bm + (i >> 3);
            int rc = min(row, N - 1);
            float4 v = *(const float4*)(X + (size_t)rc * 128 + k0 + xf * 4);
            int m = i >> 3;
            sX[xf * 4 + 0][m] = v.x;
            sX[xf * 4 + 1][m] = v.y;
            sX[xf * 4 + 2][m] = v.z;
            sX[xf * 4 + 3][m] = v.w;
        }
        #pragma unroll
        for (int it = 0; it < 4; ++it) {
            int i = tid + it * 256;
            int wr = i >> 5;
            int wf = i & 31;
            *(float4*)(&sW[wr][wf * 4]) =
                *(const float4*)(W + (size_t)(k0 + wr) * 128 + wf * 4);
        }
        __syncthreads();
        #pragma unroll
        for (int kk = 0; kk < 32; ++kk) {
            float4 a0 = *(const float4*)(&sX[kk][m0]);
            float4 a1 = *(const float4*)(&sX[kk][m0 + 4]);
            float4 b0 = *(const float4*)(&sW[kk][c4]);
            float4 b1 = *(const float4*)(&sW[kk][64 + c4]);
            float av[8] = {a0.x, a0.y, a0.z, a0.w, a1.x, a1.y, a1.z, a1.w};
            float bv[8] = {b0.x, b0.y, b0.z, b0.w, b1.x, b1.y, b1.z, b1.w};
            #pragma unroll
            for (int r = 0; r < 8; ++r)
                #pragma unroll
                for (int c = 0; c < 8; ++c)
                    acc[r][c] = fmaf(av[r], bv[c], acc[r][c]);
        }
        __syncthreads();
    }
    #pragma unroll
    for (int r = 0; r < 8; ++r) {
        int row = bm + m0 + r;
        if (row < N) {
            ushort4 o0 = {f2bf_rne(acc[r][0]), f2bf_rne(acc[r][1]),
                          f2bf_rne(acc[r][2]), f2bf_rne(acc[r][3])};
            ushort4 o1 = {f2bf_rne(acc[r][4]), f2bf_rne(acc[r][5]),
                          f2bf_rne(acc[r][6]), f2bf_rne(acc[r][7])};
            *(ushort4*)(Y + (size_t)row * 128 + c4)      = o0;
            *(ushort4*)(Y + (size_t)row * 128 + 64 + c4) = o1;
        }
    }
}

// ---- FUSED BM=16: agg (16 dst rows -> LDS fp32, +bias, ReLU) then
//      Ybf16[16,128] = sA @ W[128,128].  Grid 3125, ~6 blocks/CU resident.
__global__ __launch_bounds__(256) void k_ag128(
        const ushort_t* __restrict__ XW, const int* __restrict__ rowptr,
        const int2* __restrict__ csr, const float* __restrict__ dinv,
        const float* __restrict__ bias, const float* __restrict__ W,
        ushort_t* __restrict__ Y, int n) {
    __shared__ float sA[16][130];   // fp32 h rows; phase-B reads are broadcast
    __shared__ float sW[32][128];
    const int tid = threadIdx.x;
    const int lane = tid & 63;
    const int wv = tid >> 6;
    const int bm = blockIdx.x * 16;
    const uint_t* xw = (const uint_t*)XW;   // row stride 64 uints (256 B)
    // ---- phase A: wave wv aggregates rows [wv*4, wv*4+4) ----
    #pragma unroll 1
    for (int mi = 0; mi < 4; ++mi) {
        const int m = wv * 4 + mi;
        const int d = bm + m;
        if (d >= n) break;              // rows monotone; all reach barrier
        float dv = dinv[d];
        float w0 = dv * dv;
        uint_t sq = xw[(size_t)d * 64 + lane];
        float2 a;
        a.x = w0 * bflo(sq);
        a.y = w0 * bfhi(sq);
        int j = rowptr[d], end = rowptr[d + 1];
        for (; j + 8 <= end; j += 8) {
            int2 p0 = csr[j + 0], p1 = csr[j + 1], p2 = csr[j + 2], p3 = csr[j + 3];
            int2 p4 = csr[j + 4], p5 = csr[j + 5], p6 = csr[j + 6], p7 = csr[j + 7];
            uint_t u0 = xw[(size_t)p0.x * 64 + lane];
            uint_t u1 = xw[(size_t)p1.x * 64 + lane];
            uint_t u2 = xw[(size_t)p2.x * 64 + lane];
            uint_t u3 = xw[(size_t)p3.x * 64 + lane];
            uint_t u4 = xw[(size_t)p4.x * 64 + lane];
            uint_t u5 = xw[(size_t)p5.x * 64 + lane];
            uint_t u6 = xw[(size_t)p6.x * 64 + lane];
            uint_t u7 = xw[(size_t)p7.x * 64 + lane];
            float w0e = __int_as_float(p0.y), w1e = __int_as_float(p1.y);
            float w2e = __int_as_float(p2.y), w3e = __int_as_float(p3.y);
            float w4e = __int_as_float(p4.y), w5e = __int_as_float(p5.y);
            float w6e = __int_as_float(p6.y), w7e = __int_as_float(p7.y);
            a.x = fmaf(w0e, bflo(u0), a.x); a.y = fmaf(w0e, bfhi(u0), a.y);
            a.x = fmaf(w1e, bflo(u1), a.x); a.y = fmaf(w1e, bfhi(u1), a.y);
            a.x = fmaf(w2e, bflo(u2), a.x); a.y = fmaf(w2e, bfhi(u2), a.y);
            a.x = fmaf(w3e, bflo(u3), a.x); a.y = fmaf(w3e, bfhi(u3), a.y);
            a.x = fmaf(w4e, bflo(u4), a.x); a.y = fmaf(w4e, bfhi(u4), a.y);
            a.x = fmaf(w5e, bflo(u5), a.x); a.y = fmaf(w5e, bfhi(u5), a.y);
            a.x = fmaf(w6e, bflo(u6), a.x); a.y = fmaf(w6e, bfhi(u6), a.y);
            a.x = fmaf(w7e, bflo(u7), a.x); a.y = fmaf(w7e, bfhi(u7), a.y);
        }
        for (; j < end; ++j) {
            int2 p = csr[j];
            float we = __int_as_float(p.y);
            uint_t u = xw[(size_t)p.x * 64 + lane];
            a.x = fmaf(we, bflo(u), a.x);
            a.y = fmaf(we, bfhi(u), a.y);
        }
        float2 b = ((const float2*)bias)[lane];
        a.x = fmaxf(a.x + b.x, 0.f);
        a.y = fmaxf(a.y + b.y, 0.f);
        *(float2*)(&sA[m][lane * 2]) = a;
    }
    __syncthreads();
    // ---- phase B: 16x128 GEMM from LDS; 2 rows x 4 cols per thread ----
    const int mg = (tid >> 5) * 2;      // 0,2,...,14 (wave-uniform per half)
    const int c4 = (tid & 31) * 4;      // 0..124
    float acc[2][4] = {};
    for (int k0 = 0; k0 < 128; k0 += 32) {
        #pragma unroll
        for (int it = 0; it < 4; ++it) {
            int i = tid + it * 256;
            int wr = i >> 5;
            int wf = i & 31;
            *(float4*)(&sW[wr][wf * 4]) =
                *(const float4*)(W + (size_t)(k0 + wr) * 128 + wf * 4);
        }
        __syncthreads();
        #pragma unroll
        for (int kk = 0; kk < 32; ++kk) {
            float a0 = sA[mg][k0 + kk];       // broadcast within half-wave
            float a1 = sA[mg + 1][k0 + kk];
            float4 b = *(const float4*)(&sW[kk][c4]);
            acc[0][0] = fmaf(a0, b.x, acc[0][0]);
            acc[0][1] = fmaf(a0, b.y, acc[0][1]);
            acc[0][2] = fmaf(a0, b.z, acc[0][2]);
            acc[0][3] = fmaf(a0, b.w, acc[0][3]);
            acc[1][0] = fmaf(a1, b.x, acc[1][0]);
            acc[1][1] = fmaf(a1, b.y, acc[1][1]);
            acc[1][2] = fmaf(a1, b.z, acc[1][2]);
            acc[1][3] = fmaf(a1, b.w, acc[1][3]);
        }
        __syncthreads();
    }
    #pragma unroll
    for (int r = 0; r < 2; ++r) {
        int row = bm + mg + r;
        if (row < n) {
            ushort4 o = {f2bf_rne(acc[r][0]), f2bf_rne(acc[r][1]),
                         f2bf_rne(acc[r][2]), f2bf_rne(acc[r][3])};
            *(ushort4*)(Y + (size_t)row * 128 + c4) = o;
        }
    }
}

// ---- FUSED BM=16: agg (16 rows, +bias, ReLU) then
//      Ybf16[16,40(stride 64)] = sA @ W[128,40].  W3 staged once (20.5 KB).
__global__ __launch_bounds__(256) void k_ag40(
        const ushort_t* __restrict__ XW, const int* __restrict__ rowptr,
        const int2* __restrict__ csr, const float* __restrict__ dinv,
        const float* __restrict__ bias, const float* __restrict__ W,
        ushort_t* __restrict__ Y, int n) {
    __shared__ float sA[16][130];
    __shared__ float sW[128][40];
    const int tid = threadIdx.x;
    const int lane = tid & 63;
    const int wv = tid >> 6;
    const int bm = blockIdx.x * 16;
    const uint_t* xw = (const uint_t*)XW;
    // stage all of W3 while phase A runs its first loads
    for (int i = tid; i < 1280; i += 256) {
        int wr = i / 10;
        int wf = i - wr * 10;
        *(float4*)(&sW[wr][wf * 4]) = *(const float4*)(W + (size_t)wr * 40 + wf * 4);
    }
    #pragma unroll 1
    for (int mi = 0; mi < 4; ++mi) {
        const int m = wv * 4 + mi;
        const int d = bm + m;
        if (d >= n) break;
        float dv = dinv[d];
        float w0 = dv * dv;
        uint_t sq = xw[(size_t)d * 64 + lane];
        float2 a;
        a.x = w0 * bflo(sq);
        a.y = w0 * bfhi(sq);
        int j = rowptr[d], end = rowptr[d + 1];
        for (; j + 8 <= end; j += 8) {
            int2 p0 = csr[j + 0], p1 = csr[j + 1], p2 = csr[j + 2], p3 = csr[j + 3];
            int2 p4 = csr[j + 4], p5 = csr[j + 5], p6 = csr[j + 6], p7 = csr[j + 7];
            uint_t u0 = xw[(size_t)p0.x * 64 + lane];
            uint_t u1 = xw[(size_t)p1.x * 64 + lane];
            uint_t u2 = xw[(size_t)p2.x * 64 + lane];
            uint_t u3 = xw[(size_t)p3.x * 64 + lane];
            uint_t u4 = xw[(size_t)p4.x * 64 + lane];
            uint_t u5 = xw[(size_t)p5.x * 64 + lane];
            uint_t u6 = xw[(size_t)p6.x * 64 + lane];
            uint_t u7 = xw[(size_t)p7.x * 64 + lane];
            float w0e = __int_as_float(p0.y), w1e = __int_as_float(p1.y);
            float w2e = __int_as_float(p2.y), w3e = __int_as_float(p3.y);
            float w4e = __int_as_float(p4.y), w5e = __int_as_float(p5.y);
            float w6e = __int_as_float(p6.y), w7e = __int_as_float(p7.y);
            a.x = fmaf(w0e, bflo(u0), a.x); a.y = fmaf(w0e, bfhi(u0), a.y);
            a.x = fmaf(w1e, bflo(u1), a.x); a.y = fmaf(w1e, bfhi(u1), a.y);
            a.x = fmaf(w2e, bflo(u2), a.x); a.y = fmaf(w2e, bfhi(u2), a.y);
            a.x = fmaf(w3e, bflo(u3), a.x); a.y = fmaf(w3e, bfhi(u3), a.y);
            a.x = fmaf(w4e, bflo(u4), a.x); a.y = fmaf(w4e, bfhi(u4), a.y);
            a.x = fmaf(w5e, bflo(u5), a.x); a.y = fmaf(w5e, bfhi(u5), a.y);
            a.x = fmaf(w6e, bflo(u6), a.x); a.y = fmaf(w6e, bfhi(u6), a.y);
            a.x = fmaf(w7e, bflo(u7), a.x); a.y = fmaf(w7e, bfhi(u7), a.y);
        }
        for (; j < end; ++j) {
            int2 p = csr[j];
            float we = __int_as_float(p.y);
            uint_t u = xw[(size_t)p.x * 64 + lane];
            a.x = fmaf(we, bflo(u), a.x);
            a.y = fmaf(we, bfhi(u), a.y);
        }
        float2 b = ((const float2*)bias)[lane];
        a.x = fmaxf(a.x + b.x, 0.f);
        a.y = fmaxf(a.y + b.y, 0.f);
        *(float2*)(&sA[m][lane * 2]) = a;
    }
    __syncthreads();
    // ---- phase B: 16x40 from LDS; threads 0..127: 1 row x 5 cols ----
    if (tid < 128) {
        const int r = tid >> 3;             // 0..15
        const int c0 = (tid & 7) * 5;       // 0,5,...,35
        float acc[5] = {};
        #pragma unroll 4
        for (int kk = 0; kk < 128; ++kk) {
            float a = sA[r][kk];            // broadcast within 8-lane group
            #pragma unroll
            for (int c = 0; c < 5; ++c)
                acc[c] = fmaf(a, sW[kk][c0 + c], acc[c]);
        }
        int row = bm + r;
        if (row < n) {
            #pragma unroll
            for (int c = 0; c < 5; ++c)
                Y[(size_t)row * 64 + c0 + c] = f2bf_rne(acc[c]);
        }
    }
}

// Half-wave per dst, F=40 bf16 rows padded to stride 64 (R14 form).
__global__ __launch_bounds__(256) void k_agg40(
        const ushort_t* __restrict__ XW, const int* __restrict__ rowptr,
        const int2* __restrict__ csr, const float* __restrict__ dinv,
        const float* __restrict__ bias, float* __restrict__ out, int n) {
    const int lane = threadIdx.x & 31;
    const int sub  = threadIdx.x >> 5;
    const int d = blockIdx.x * 8 + sub;
    if (d >= n || lane >= 20) return;
    const uint_t* xw = (const uint_t*)XW;       // row stride 32 uints
    float dv = dinv[d];
    float w0 = dv * dv;
    uint_t sq = xw[(size_t)d * 32 + lane];
    float2 a;
    a.x = w0 * bflo(sq);
    a.y = w0 * bfhi(sq);
    int j = rowptr[d], end = rowptr[d + 1];
    for (; j + 4 <= end; j += 4) {
        int2 p0 = csr[j + 0], p1 = csr[j + 1], p2 = csr[j + 2], p3 = csr[j + 3];
        uint_t u0 = xw[(size_t)p0.x * 32 + lane];
        uint_t u1 = xw[(size_t)p1.x * 32 + lane];
        uint_t u2 = xw[(size_t)p2.x * 32 + lane];
        uint_t u3 = xw[(size_t)p3.x * 32 + lane];
        float w0e = __int_as_float(p0.y), w1e = __int_as_float(p1.y);
        float w2e = __int_as_float(p2.y), w3e = __int_as_float(p3.y);
        a.x = fmaf(w0e, bflo(u0), a.x); a.y = fmaf(w0e, bfhi(u0), a.y);
        a.x = fmaf(w1e, bflo(u1), a.x); a.y = fmaf(w1e, bfhi(u1), a.y);
        a.x = fmaf(w2e, bflo(u2), a.x); a.y = fmaf(w2e, bfhi(u2), a.y);
        a.x = fmaf(w3e, bflo(u3), a.x); a.y = fmaf(w3e, bfhi(u3), a.y);
    }
    for (; j < end; ++j) {
        int2 p = csr[j];
        float we = __int_as_float(p.y);
        uint_t u = xw[(size_t)p.x * 32 + lane];
        a.x = fmaf(we, bflo(u), a.x);
        a.y = fmaf(we, bfhi(u), a.y);
    }
    float2 b = ((const float2*)bias)[lane];
    a.x += b.x; a.y += b.y;
    ((float2*)out)[(size_t)d * 20 + lane] = a;
}

static inline int cdiv(long long a, int b) { return (int)((a + b - 1) / b); }

extern "C" void kernel_launch(void* const* d_in, const int* in_sizes, int n_in,
                              void* d_out, int out_size, void* d_ws, size_t ws_size,
                              hipStream_t stream) {
    const float* x  = (const float*)d_in[0];
    const int*   ei = (const int*)d_in[1];
    const float* W1 = (const float*)d_in[2];
    const float* b1 = (const float*)d_in[3];
    const float* W2 = (const float*)d_in[4];
    const float* b2 = (const float*)d_in[5];
    const float* W3 = (const float*)d_in[6];
    const float* b3 = (const float*)d_in[7];
    float* out = (float*)d_out;

    const int N = in_sizes[0] / 128;   // 50000
    const int E = in_sizes[1] / 2;     // 800000
    const int nb = cdiv(N, 256);       // 196 scan blocks (co-resident)

    char* ws = (char*)d_ws;
    int*   deg    = (int*)ws;                 ws += (size_t)N * 4;
    unsigned long long* partials = (unsigned long long*)ws;
                                              ws += (size_t)nb * 8;
    int*   rowptr = (int*)ws;                 ws += (size_t)(N + 1) * 4;
    int*   cursor = (int*)ws;                 ws += (size_t)N * 4;
    float* dinv   = (float*)ws;               ws += (size_t)N * 4;
    ws = (char*)(((uintptr_t)ws + 127) & ~(uintptr_t)127);
    int2*     csr  = (int2*)ws;               ws += (size_t)E * 8;
    ushort_t* bufA = (ushort_t*)ws;           ws += (size_t)N * 128 * 2;
    ushort_t* bufC = (ushort_t*)ws;           ws += (size_t)N * 128 * 2;
    ushort_t* bufD = (ushort_t*)ws;

    const int BT = 256;
    const int gemmGrid = cdiv(N, 128);          // 391
    const int degGrid  = cdiv(E, BT);           // 3125

    // memset covers deg AND partials (contiguous).
    hipMemsetAsync(deg, 0, (size_t)N * 4 + (size_t)nb * 8, stream);

    // layer-1 GEMM ∪ degree count (independent work, one dispatch)
    k_l1<<<gemmGrid + degGrid, 256, 0, stream>>>(x, W1, bufA, N,
                                                 ei, deg, E, gemmGrid);
    // CSR build
    k_scan<<<nb, 256, 0, stream>>>(deg, partials, rowptr, cursor, dinv, N);
    k_fill<<<cdiv(E, BT) * 8, 256, 0, stream>>>(ei, cursor, dinv, csr, E, N);

    // fused agg1 + gemm2 ; fused agg2 + gemm3 ; final agg
    k_ag128<<<cdiv(N, 16), 256, 0, stream>>>(bufA, rowptr, csr, dinv, b1, W2, bufC, N);
    k_ag40 <<<cdiv(N, 16), 256, 0, stream>>>(bufC, rowptr, csr, dinv, b2, W3, bufD, N);
    k_agg40<<<cdiv(N, 8), 256, 0, stream>>>(bufD, rowptr, csr, dinv, b3, out, N);
}

// Round 3
// 313.935 us; speedup vs baseline: 3.2390x; 3.2390x over previous
//
#include <hip/hip_runtime.h>

typedef unsigned short ushort_t;
typedef unsigned int uint_t;

// ---------------------------------------------------------------------------
// GCN 3-layer forward.  N=50000, E=800000, D=H=128, C=40.
// Round 20: REVERT to R17 structure (best measured: 301.6us).  R18/R19
// intra-block fusion post-mortem: agg phase needs ~32+ waves/CU TLP which a
// fused block can't provide (VGPR>=88 caps 16 waves/CU; R19 additionally
// spilled at VGPR=256 -> 1.7GB scratch traffic).  Single new delta vs R17:
// non-temporal loads/stores for stream-once data (csr stream in aggs, ei in
// fill/deg, csr scatter-store in fill) so the 6.4MB/layer csr stream stops
// evicting the hot 12.8MB xw gather rows from each XCD's 4MB L2.
// Numerics bit-identical to R17 (NT affects caching only).
// ws layout: [deg:N int][partials:nb u64][rowptr:N+1][cursor:N][dinv:N f32]
//            [csr:E int2][bufA:N*128*4 B][bufB:N*128 f32]
// ---------------------------------------------------------------------------

__device__ __forceinline__ int2 ldnt2(const int2* p) {
    long long v = __builtin_nontemporal_load((const long long*)p);
    int2 r;
    r.x = (int)(v & 0xffffffffll);
    r.y = (int)(v >> 32);
    return r;
}

// Single-dispatch scan, wave-parallel decoupled lookback (R16).
__global__ __launch_bounds__(256) void k_scan(
        const int* __restrict__ deg, unsigned long long* __restrict__ partials,
        int* __restrict__ rowptr, int* __restrict__ cursor,
        float* __restrict__ dinv, int n) {
    __shared__ int s[256];
    __shared__ int sprefix;
    const int b = blockIdx.x, t = threadIdx.x;
    const int i = b * 256 + t;
    int v = (i < n) ? deg[i] : 0;
    s[t] = v;
    __syncthreads();
    for (int off = 1; off < 256; off <<= 1) {
        int u = (t >= off) ? s[t - off] : 0;
        __syncthreads();
        s[t] += u;
        __syncthreads();
    }
    if (t == 0) {
        __hip_atomic_store(&partials[b],
                ((unsigned long long)s[255] << 2) | 1ull,
                __ATOMIC_RELEASE, __HIP_MEMORY_SCOPE_AGENT);
        if (b == 0) {
            __hip_atomic_store(&partials[0],
                    ((unsigned long long)s[255] << 2) | 2ull,
                    __ATOMIC_RELEASE, __HIP_MEMORY_SCOPE_AGENT);
            sprefix = 0;
        }
    }
    if (b > 0 && t < 64) {
        int acc = 0;
        int k = b - 1;
        for (;;) {
            int idx = k - t;
            unsigned long long p;
            unsigned st;
            do {
                if (idx >= 0) {
                    p = __hip_atomic_load(&partials[idx],
                            __ATOMIC_ACQUIRE, __HIP_MEMORY_SCOPE_AGENT);
                } else {
                    p = 2ull;
                }
                st = (unsigned)(p & 3ull);
            } while (st == 0);
            unsigned long long bal = __ballot(st == 2);
            int L = (bal != 0) ? (__ffsll((unsigned long long)bal) - 1) : 64;
            int val = (int)(p >> 2);
            int contrib = (t <= L) ? val : 0;
            #pragma unroll
            for (int o = 32; o > 0; o >>= 1) contrib += __shfl_down(contrib, o);
            if (t == 0) acc += contrib;
            if (L < 64) break;
            k -= 64;
        }
        if (t == 0) {
            __hip_atomic_store(&partials[b],
                    (((unsigned long long)(acc + s[255])) << 2) | 2ull,
                    __ATOMIC_RELEASE, __HIP_MEMORY_SCOPE_AGENT);
            sprefix = acc;
        }
    }
    __syncthreads();
    if (i < n) {
        int ex = sprefix + s[t] - v;
        rowptr[i] = ex;
        cursor[i] = ex;
        dinv[i] = rsqrtf((float)(v + 1));
        if (i == n - 1) rowptr[n] = ex + v;
    }
}

// XCD-partitioned scatter (R12) + NT streams.
__global__ __launch_bounds__(256) void k_fill(const int* __restrict__ ei,
                                              int* __restrict__ cursor,
                                              const float* __restrict__ dinv,
                                              int2* __restrict__ csr, int E, int n) {
    const int xcd = blockIdx.x & 7;
    const int e = (blockIdx.x >> 3) * 256 + threadIdx.x;
    if (e >= E) return;
    int d = __builtin_nontemporal_load(ei + E + e);
    const int lo = (int)(((long long)xcd * n) >> 3);
    const int hi = (int)(((long long)(xcd + 1) * n) >> 3);
    if (d < lo || d >= hi) return;
    int s = __builtin_nontemporal_load(ei + e);
    int pos = atomicAdd(&cursor[d], 1);
    unsigned long long packed = (unsigned long long)(unsigned)s |
            ((unsigned long long)(unsigned)__float_as_uint(dinv[s] * dinv[d]) << 32);
    __builtin_nontemporal_store((long long)packed, (long long*)(csr + pos));
}

__device__ __forceinline__ ushort_t f2bf_rne(float f) {
    uint_t u = __float_as_uint(f);
    u += 0x7fffu + ((u >> 16) & 1u);
    return (ushort_t)(u >> 16);
}
__device__ __forceinline__ float bflo(uint_t u) {
    return __uint_as_float(u << 16);
}
__device__ __forceinline__ float bfhi(uint_t u) {
    return __uint_as_float(u & 0xffff0000u);
}

// ---- UNION: blocks [0,gemmGrid) = Ybf16[N,128]=X@W1 (BM=128, 8x8 utile);
//      blocks [gemmGrid, ...) = deg_count (1 edge/thread).  Independent work.
__global__ __launch_bounds__(256) void k_l1(const float* __restrict__ X,
                                            const float* __restrict__ W,
                                            ushort_t* __restrict__ Y, int N,
                                            const int* __restrict__ ei,
                                            int* __restrict__ deg, int E,
                                            int gemmGrid) {
    __shared__ float sX[32][132];
    __shared__ float sW[32][128];
    if ((int)blockIdx.x >= gemmGrid) {
        int e = ((int)blockIdx.x - gemmGrid) * 256 + threadIdx.x;
        if (e < E) atomicAdd(&deg[__builtin_nontemporal_load(ei + E + e)], 1);
        return;
    }
    const int tid = threadIdx.x;
    const int bm = blockIdx.x * 128;
    const int m0 = (tid >> 4) * 8;
    const int c4 = (tid & 15) * 4;
    const int xf = tid & 7;
    float acc[8][8] = {};
    for (int k0 = 0; k0 < 128; k0 += 32) {
        #pragma unroll
        for (int it = 0; it < 4; ++it) {
            int i = tid + it * 256;
            int row = bm + (i >> 3);
            int rc = min(row, N - 1);
            float4 v = *(const float4*)(X + (size_t)rc * 128 + k0 + xf * 4);
            int m = i >> 3;
            sX[xf * 4 + 0][m] = v.x;
            sX[xf * 4 + 1][m] = v.y;
            sX[xf * 4 + 2][m] = v.z;
            sX[xf * 4 + 3][m] = v.w;
        }
        #pragma unroll
        for (int it = 0; it < 4; ++it) {
            int i = tid + it * 256;
            int wr = i >> 5;
            int wf = i & 31;
            *(float4*)(&sW[wr][wf * 4]) =
                *(const float4*)(W + (size_t)(k0 + wr) * 128 + wf * 4);
        }
        __syncthreads();
        #pragma unroll
        for (int kk = 0; kk < 32; ++kk) {
            float4 a0 = *(const float4*)(&sX[kk][m0]);
            float4 a1 = *(const float4*)(&sX[kk][m0 + 4]);
            float4 b0 = *(const float4*)(&sW[kk][c4]);
            float4 b1 = *(const float4*)(&sW[kk][64 + c4]);
            float av[8] = {a0.x, a0.y, a0.z, a0.w, a1.x, a1.y, a1.z, a1.w};
            float bv[8] = {b0.x, b0.y, b0.z, b0.w, b1.x, b1.y, b1.z, b1.w};
            #pragma unroll
            for (int r = 0; r < 8; ++r)
                #pragma unroll
                for (int c = 0; c < 8; ++c)
                    acc[r][c] = fmaf(av[r], bv[c], acc[r][c]);
        }
        __syncthreads();
    }
    #pragma unroll
    for (int r = 0; r < 8; ++r) {
        int row = bm + m0 + r;
        if (row < N) {
            ushort4 o0 = {f2bf_rne(acc[r][0]), f2bf_rne(acc[r][1]),
                          f2bf_rne(acc[r][2]), f2bf_rne(acc[r][3])};
            ushort4 o1 = {f2bf_rne(acc[r][4]), f2bf_rne(acc[r][5]),
                          f2bf_rne(acc[r][6]), f2bf_rne(acc[r][7])};
            *(ushort4*)(Y + (size_t)row * 128 + c4)      = o0;
            *(ushort4*)(Y + (size_t)row * 128 + 64 + c4) = o1;
        }
    }
}

// ---- Ybf16[N,128] = X[N,128] @ W[128,128].  BM=128, BK=32; 8x8 microtile.
__global__ __launch_bounds__(256) void k_gemm128(const float* __restrict__ X,
                                                 const float* __restrict__ W,
                                                 ushort_t* __restrict__ Y, int N) {
    __shared__ float sX[32][132];
    __shared__ float sW[32][128];
    const int tid = threadIdx.x;
    const int bm = blockIdx.x * 128;
    const int m0 = (tid >> 4) * 8;
    const int c4 = (tid & 15) * 4;
    const int xf = tid & 7;
    float acc[8][8] = {};
    for (int k0 = 0; k0 < 128; k0 += 32) {
        #pragma unroll
        for (int it = 0; it < 4; ++it) {
            int i = tid + it * 256;
            int row = bm + (i >> 3);
            int rc = min(row, N - 1);
            float4 v = *(const float4*)(X + (size_t)rc * 128 + k0 + xf * 4);
            int m = i >> 3;
            sX[xf * 4 + 0][m] = v.x;
            sX[xf * 4 + 1][m] = v.y;
            sX[xf * 4 + 2][m] = v.z;
            sX[xf * 4 + 3][m] = v.w;
        }
        #pragma unroll
        for (int it = 0; it < 4; ++it) {
            int i = tid + it * 256;
            int wr = i >> 5;
            int wf = i & 31;
            *(float4*)(&sW[wr][wf * 4]) =
                *(const float4*)(W + (size_t)(k0 + wr) * 128 + wf * 4);
        }
        __syncthreads();
        #pragma unroll
        for (int kk = 0; kk < 32; ++kk) {
            float4 a0 = *(const float4*)(&sX[kk][m0]);
            float4 a1 = *(const float4*)(&sX[kk][m0 + 4]);
            float4 b0 = *(const float4*)(&sW[kk][c4]);
            float4 b1 = *(const float4*)(&sW[kk][64 + c4]);
            float av[8] = {a0.x, a0.y, a0.z, a0.w, a1.x, a1.y, a1.z, a1.w};
            float bv[8] = {b0.x, b0.y, b0.z, b0.w, b1.x, b1.y, b1.z, b1.w};
            #pragma unroll
            for (int r = 0; r < 8; ++r)
                #pragma unroll
                for (int c = 0; c < 8; ++c)
                    acc[r][c] = fmaf(av[r], bv[c], acc[r][c]);
        }
        __syncthreads();
    }
    #pragma unroll
    for (int r = 0; r < 8; ++r) {
        int row = bm + m0 + r;
        if (row < N) {
            ushort4 o0 = {f2bf_rne(acc[r][0]), f2bf_rne(acc[r][1]),
                          f2bf_rne(acc[r][2]), f2bf_rne(acc[r][3])};
            ushort4 o1 = {f2bf_rne(acc[r][4]), f2bf_rne(acc[r][5]),
                          f2bf_rne(acc[r][6]), f2bf_rne(acc[r][7])};
            *(ushort4*)(Y + (size_t)row * 128 + c4)      = o0;
            *(ushort4*)(Y + (size_t)row * 128 + 64 + c4) = o1;
        }
    }
}

// ---- Ybf16[N,40 (stride 64)] = X[N,128] @ W[128,40].  BM=128, BK=32. ----
__global__ __launch_bounds__(256) void k_gemm40(const float* __restrict__ X,
                                                const float* __restrict__ W,
                                                ushort_t* __restrict__ Y, int N) {
    __shared__ float sX[32][132];
    __shared__ float sW[32][40];
    const int tid = threadIdx.x;
    const int bm = blockIdx.x * 128;
    const int m0 = (tid >> 3) * 4;
    const int n0 = (tid & 7) * 5;
    const int xf = tid & 7;
    float acc[4][5] = {};
    for (int k0 = 0; k0 < 128; k0 += 32) {
        #pragma unroll
        for (int it = 0; it < 4; ++it) {
            int i = tid + it * 256;
            int row = bm + (i >> 3);
            int rc = min(row, N - 1);
            float4 v = *(const float4*)(X + (size_t)rc * 128 + k0 + xf * 4);
            int m = i >> 3;
            sX[xf * 4 + 0][m] = v.x;
            sX[xf * 4 + 1][m] = v.y;
            sX[xf * 4 + 2][m] = v.z;
            sX[xf * 4 + 3][m] = v.w;
        }
        for (int i = tid; i < 320; i += 256) {
            int wr = i / 10;
            int wf = i - wr * 10;
            *(float4*)(&sW[wr][wf * 4]) =
                *(const float4*)(W + (size_t)(k0 + wr) * 40 + wf * 4);
        }
        __syncthreads();
        #pragma unroll
        for (int kk = 0; kk < 32; ++kk) {
            float4 a = *(const float4*)(&sX[kk][m0]);
            float av[4] = {a.x, a.y, a.z, a.w};
            #pragma unroll
            for (int c = 0; c < 5; ++c) {
                float b = sW[kk][n0 + c];
                #pragma unroll
                for (int r = 0; r < 4; ++r)
                    acc[r][c] = fmaf(av[r], b, acc[r][c]);
            }
        }
        __syncthreads();
    }
    #pragma unroll
    for (int r = 0; r < 4; ++r) {
        int row = bm + m0 + r;
        if (row < N) {
            #pragma unroll
            for (int c = 0; c < 5; ++c)
                Y[(size_t)row * 64 + n0 + c] = f2bf_rne(acc[r][c]);
        }
    }
}

// Uniform full-wave agg, F=128 bf16 (R14 form, unroll 8) + NT csr stream.
template <bool RELU>
__global__ __launch_bounds__(256) void k_agg128(
        const ushort_t* __restrict__ XW, const int* __restrict__ rowptr,
        const int2* __restrict__ csr, const float* __restrict__ dinv,
        const float* __restrict__ bias, float* __restrict__ out, int n) {
    const int lane = threadIdx.x & 63;
    const int wv = __builtin_amdgcn_readfirstlane(threadIdx.x >> 6);
    const int d = blockIdx.x * 4 + wv;
    if (d >= n) return;
    const uint_t* xw = (const uint_t*)XW;           // row stride 64 uints (256 B)
    float dv = dinv[d];
    float w0 = dv * dv;
    uint_t sq = xw[(size_t)d * 64 + lane];
    float2 a;
    a.x = w0 * bflo(sq);
    a.y = w0 * bfhi(sq);
    int j = rowptr[d], end = rowptr[d + 1];
    for (; j + 8 <= end; j += 8) {
        int2 p0 = ldnt2(csr + j + 0), p1 = ldnt2(csr + j + 1);
        int2 p2 = ldnt2(csr + j + 2), p3 = ldnt2(csr + j + 3);
        int2 p4 = ldnt2(csr + j + 4), p5 = ldnt2(csr + j + 5);
        int2 p6 = ldnt2(csr + j + 6), p7 = ldnt2(csr + j + 7);
        uint_t u0 = xw[(size_t)p0.x * 64 + lane];
        uint_t u1 = xw[(size_t)p1.x * 64 + lane];
        uint_t u2 = xw[(size_t)p2.x * 64 + lane];
        uint_t u3 = xw[(size_t)p3.x * 64 + lane];
        uint_t u4 = xw[(size_t)p4.x * 64 + lane];
        uint_t u5 = xw[(size_t)p5.x * 64 + lane];
        uint_t u6 = xw[(size_t)p6.x * 64 + lane];
        uint_t u7 = xw[(size_t)p7.x * 64 + lane];
        float w0e = __int_as_float(p0.y), w1e = __int_as_float(p1.y);
        float w2e = __int_as_float(p2.y), w3e = __int_as_float(p3.y);
        float w4e = __int_as_float(p4.y), w5e = __int_as_float(p5.y);
        float w6e = __int_as_float(p6.y), w7e = __int_as_float(p7.y);
        a.x = fmaf(w0e, bflo(u0), a.x); a.y = fmaf(w0e, bfhi(u0), a.y);
        a.x = fmaf(w1e, bflo(u1), a.x); a.y = fmaf(w1e, bfhi(u1), a.y);
        a.x = fmaf(w2e, bflo(u2), a.x); a.y = fmaf(w2e, bfhi(u2), a.y);
        a.x = fmaf(w3e, bflo(u3), a.x); a.y = fmaf(w3e, bfhi(u3), a.y);
        a.x = fmaf(w4e, bflo(u4), a.x); a.y = fmaf(w4e, bfhi(u4), a.y);
        a.x = fmaf(w5e, bflo(u5), a.x); a.y = fmaf(w5e, bfhi(u5), a.y);
        a.x = fmaf(w6e, bflo(u6), a.x); a.y = fmaf(w6e, bfhi(u6), a.y);
        a.x = fmaf(w7e, bflo(u7), a.x); a.y = fmaf(w7e, bfhi(u7), a.y);
    }
    for (; j < end; ++j) {
        int2 p = ldnt2(csr + j);
        float we = __int_as_float(p.y);
        uint_t u = xw[(size_t)p.x * 64 + lane];
        a.x = fmaf(we, bflo(u), a.x);
        a.y = fmaf(we, bfhi(u), a.y);
    }
    float2 b = ((const float2*)bias)[lane];
    a.x += b.x; a.y += b.y;
    if (RELU) {
        a.x = fmaxf(a.x, 0.f);
        a.y = fmaxf(a.y, 0.f);
    }
    ((float2*)out)[(size_t)d * 64 + lane] = a;
}

// Half-wave per dst, F=40 bf16 rows padded to stride 64 (R14 form) + NT csr.
__global__ __launch_bounds__(256) void k_agg40(
        const ushort_t* __restrict__ XW, const int* __restrict__ rowptr,
        const int2* __restrict__ csr, const float* __restrict__ dinv,
        const float* __restrict__ bias, float* __restrict__ out, int n) {
    const int lane = threadIdx.x & 31;
    const int sub  = threadIdx.x >> 5;
    const int d = blockIdx.x * 8 + sub;
    if (d >= n || lane >= 20) return;
    const uint_t* xw = (const uint_t*)XW;       // row stride 32 uints
    float dv = dinv[d];
    float w0 = dv * dv;
    uint_t sq = xw[(size_t)d * 32 + lane];
    float2 a;
    a.x = w0 * bflo(sq);
    a.y = w0 * bfhi(sq);
    int j = rowptr[d], end = rowptr[d + 1];
    for (; j + 4 <= end; j += 4) {
        int2 p0 = ldnt2(csr + j + 0), p1 = ldnt2(csr + j + 1);
        int2 p2 = ldnt2(csr + j + 2), p3 = ldnt2(csr + j + 3);
        uint_t u0 = xw[(size_t)p0.x * 32 + lane];
        uint_t u1 = xw[(size_t)p1.x * 32 + lane];
        uint_t u2 = xw[(size_t)p2.x * 32 + lane];
        uint_t u3 = xw[(size_t)p3.x * 32 + lane];
        float w0e = __int_as_float(p0.y), w1e = __int_as_float(p1.y);
        float w2e = __int_as_float(p2.y), w3e = __int_as_float(p3.y);
        a.x = fmaf(w0e, bflo(u0), a.x); a.y = fmaf(w0e, bfhi(u0), a.y);
        a.x = fmaf(w1e, bflo(u1), a.x); a.y = fmaf(w1e, bfhi(u1), a.y);
        a.x = fmaf(w2e, bflo(u2), a.x); a.y = fmaf(w2e, bfhi(u2), a.y);
        a.x = fmaf(w3e, bflo(u3), a.x); a.y = fmaf(w3e, bfhi(u3), a.y);
    }
    for (; j < end; ++j) {
        int2 p = ldnt2(csr + j);
        float we = __int_as_float(p.y);
        uint_t u = xw[(size_t)p.x * 32 + lane];
        a.x = fmaf(we, bflo(u), a.x);
        a.y = fmaf(we, bfhi(u), a.y);
    }
    float2 b = ((const float2*)bias)[lane];
    a.x += b.x; a.y += b.y;
    ((float2*)out)[(size_t)d * 20 + lane] = a;
}

static inline int cdiv(long long a, int b) { return (int)((a + b - 1) / b); }

extern "C" void kernel_launch(void* const* d_in, const int* in_sizes, int n_in,
                              void* d_out, int out_size, void* d_ws, size_t ws_size,
                              hipStream_t stream) {
    const float* x  = (const float*)d_in[0];
    const int*   ei = (const int*)d_in[1];
    const float* W1 = (const float*)d_in[2];
    const float* b1 = (const float*)d_in[3];
    const float* W2 = (const float*)d_in[4];
    const float* b2 = (const float*)d_in[5];
    const float* W3 = (const float*)d_in[6];
    const float* b3 = (const float*)d_in[7];
    float* out = (float*)d_out;

    const int N = in_sizes[0] / 128;   // 50000
    const int E = in_sizes[1] / 2;     // 800000
    const int nb = cdiv(N, 256);       // 196 scan blocks (co-resident)

    char* ws = (char*)d_ws;
    int*   deg    = (int*)ws;                 ws += (size_t)N * 4;
    unsigned long long* partials = (unsigned long long*)ws;
                                              ws += (size_t)nb * 8;
    int*   rowptr = (int*)ws;                 ws += (size_t)(N + 1) * 4;
    int*   cursor = (int*)ws;                 ws += (size_t)N * 4;
    float* dinv   = (float*)ws;               ws += (size_t)N * 4;
    ws = (char*)(((uintptr_t)ws + 127) & ~(uintptr_t)127);
    int2*  csr    = (int2*)ws;                ws += (size_t)E * 8;
    char*  bufA   = ws;                       ws += (size_t)N * 128 * 4;
    float* bufB   = (float*)ws;

    const int BT = 256;
    const int gemmGrid = cdiv(N, 128);          // 391
    const int degGrid  = cdiv(E, BT);           // 3125

    // memset covers deg AND partials (contiguous).
    hipMemsetAsync(deg, 0, (size_t)N * 4 + (size_t)nb * 8, stream);

    // layer-1 GEMM ∪ degree count (independent work, one dispatch)
    k_l1<<<gemmGrid + degGrid, 256, 0, stream>>>(x, W1, (ushort_t*)bufA, N,
                                                 ei, deg, E, gemmGrid);
    // CSR build
    k_scan<<<nb, 256, 0, stream>>>(deg, partials, rowptr, cursor, dinv, N);
    k_fill<<<cdiv(E, BT) * 8, 256, 0, stream>>>(ei, cursor, dinv, csr, E, N);

    // layer 1 aggregation
    k_agg128<true><<<cdiv(N, 4), 256, 0, stream>>>((const ushort_t*)bufA, rowptr, csr, dinv, b1, bufB, N);
    // layer 2
    k_gemm128<<<cdiv(N, 128), 256, 0, stream>>>(bufB, W2, (ushort_t*)bufA, N);
    k_agg128<true><<<cdiv(N, 4), 256, 0, stream>>>((const ushort_t*)bufA, rowptr, csr, dinv, b2, bufB, N);
    // layer 3
    k_gemm40<<<cdiv(N, 128), 256, 0, stream>>>(bufB, W3, (ushort_t*)bufA, N);
    k_agg40<<<cdiv(N, 8), 256, 0, stream>>>((const ushort_t*)bufA, rowptr, csr, dinv, b3, out, N);
}

// Round 5
// 312.399 us; speedup vs baseline: 3.2550x; 1.0049x over previous
//
#include <hip/hip_runtime.h>

typedef unsigned short ushort_t;
typedef unsigned int uint_t;
typedef int int4v __attribute__((ext_vector_type(4)));

// ---------------------------------------------------------------------------
// GCN 3-layer forward.  N=50000, E=800000, D=H=128, C=40.
// Round 22 (= R21 + compile fix: ext_vector_type for nontemporal int4 load).
// R20 post-mortem — NT store on csr caused 10x write amplification
// (WRITE_SIZE 62.5MB vs 6.4MB logical; scattered 8B NT stores push full
// lines to HBM, bypassing L2 coalescing).  Fixes:
//  (1) csr stores go back through L2 (normal store);
//  (2) csr slims to src-only (4B/edge): weight dinv[s]*dinv[d] is recomputed
//      in the aggs (dinv[d] in-register, dinv[s] = L2 load) — bit-identical
//      fp32 chain, halves fill store + agg csr stream, and drops both dinv
//      gathers from fill's latency chain;
//  (3) fill processes 4 edges/thread via int4 dst loads (4-way ILP on the
//      atomic->store chain).
// NT loads kept on pure read-streams (ei, csr) — they protect L2, can't
// amplify writes.  Everything else identical to R17/R20.
// ws layout: [deg:N int][partials:nb u64][rowptr:N+1][cursor:N][dinv:N f32]
//            [csr:E int][bufA:N*128*4 B][bufB:N*128 f32]
// ---------------------------------------------------------------------------

// Single-dispatch scan, wave-parallel decoupled lookback (R16).
__global__ __launch_bounds__(256) void k_scan(
        const int* __restrict__ deg, unsigned long long* __restrict__ partials,
        int* __restrict__ rowptr, int* __restrict__ cursor,
        float* __restrict__ dinv, int n) {
    __shared__ int s[256];
    __shared__ int sprefix;
    const int b = blockIdx.x, t = threadIdx.x;
    const int i = b * 256 + t;
    int v = (i < n) ? deg[i] : 0;
    s[t] = v;
    __syncthreads();
    for (int off = 1; off < 256; off <<= 1) {
        int u = (t >= off) ? s[t - off] : 0;
        __syncthreads();
        s[t] += u;
        __syncthreads();
    }
    if (t == 0) {
        __hip_atomic_store(&partials[b],
                ((unsigned long long)s[255] << 2) | 1ull,
                __ATOMIC_RELEASE, __HIP_MEMORY_SCOPE_AGENT);
        if (b == 0) {
            __hip_atomic_store(&partials[0],
                    ((unsigned long long)s[255] << 2) | 2ull,
                    __ATOMIC_RELEASE, __HIP_MEMORY_SCOPE_AGENT);
            sprefix = 0;
        }
    }
    if (b > 0 && t < 64) {
        int acc = 0;
        int k = b - 1;
        for (;;) {
            int idx = k - t;
            unsigned long long p;
            unsigned st;
            do {
                if (idx >= 0) {
                    p = __hip_atomic_load(&partials[idx],
                            __ATOMIC_ACQUIRE, __HIP_MEMORY_SCOPE_AGENT);
                } else {
                    p = 2ull;
                }
                st = (unsigned)(p & 3ull);
            } while (st == 0);
            unsigned long long bal = __ballot(st == 2);
            int L = (bal != 0) ? (__ffsll((unsigned long long)bal) - 1) : 64;
            int val = (int)(p >> 2);
            int contrib = (t <= L) ? val : 0;
            #pragma unroll
            for (int o = 32; o > 0; o >>= 1) contrib += __shfl_down(contrib, o);
            if (t == 0) acc += contrib;
            if (L < 64) break;
            k -= 64;
        }
        if (t == 0) {
            __hip_atomic_store(&partials[b],
                    (((unsigned long long)(acc + s[255])) << 2) | 2ull,
                    __ATOMIC_RELEASE, __HIP_MEMORY_SCOPE_AGENT);
            sprefix = acc;
        }
    }
    __syncthreads();
    if (i < n) {
        int ex = sprefix + s[t] - v;
        rowptr[i] = ex;
        cursor[i] = ex;
        dinv[i] = rsqrtf((float)(v + 1));
        if (i == n - 1) rowptr[n] = ex + v;
    }
}

// XCD-partitioned scatter (R12), 4 edges/thread, src-only csr.
__global__ __launch_bounds__(256) void k_fill(const int* __restrict__ ei,
                                              int* __restrict__ cursor,
                                              int* __restrict__ csr, int E, int n) {
    const int xcd = blockIdx.x & 7;
    const int e4 = (((blockIdx.x >> 3) * 256 + threadIdx.x) << 2);
    if (e4 >= E) return;
    const int lo = (int)(((long long)xcd * n) >> 3);
    const int hi = (int)(((long long)(xcd + 1) * n) >> 3);
    if (e4 + 4 <= E) {
        int4v d4 = __builtin_nontemporal_load((const int4v*)(ei + E + e4));
        #pragma unroll
        for (int k = 0; k < 4; ++k) {
            int d = d4[k];
            if (d >= lo && d < hi) {
                int s = __builtin_nontemporal_load(ei + e4 + k);
                int pos = atomicAdd(&cursor[d], 1);
                csr[pos] = s;                       // normal store: L2 coalesces
            }
        }
    } else {
        for (int k = 0; k < 4 && e4 + k < E; ++k) {
            int d = __builtin_nontemporal_load(ei + E + e4 + k);
            if (d >= lo && d < hi) {
                int s = __builtin_nontemporal_load(ei + e4 + k);
                int pos = atomicAdd(&cursor[d], 1);
                csr[pos] = s;
            }
        }
    }
}

__device__ __forceinline__ ushort_t f2bf_rne(float f) {
    uint_t u = __float_as_uint(f);
    u += 0x7fffu + ((u >> 16) & 1u);
    return (ushort_t)(u >> 16);
}
__device__ __forceinline__ float bflo(uint_t u) {
    return __uint_as_float(u << 16);
}
__device__ __forceinline__ float bfhi(uint_t u) {
    return __uint_as_float(u & 0xffff0000u);
}

// ---- UNION: blocks [0,gemmGrid) = Ybf16[N,128]=X@W1 (BM=128, 8x8 utile);
//      blocks [gemmGrid, ...) = deg_count (1 edge/thread).  Independent work.
__global__ __launch_bounds__(256) void k_l1(const float* __restrict__ X,
                                            const float* __restrict__ W,
                                            ushort_t* __restrict__ Y, int N,
                                            const int* __restrict__ ei,
                                            int* __restrict__ deg, int E,
                                            int gemmGrid) {
    __shared__ float sX[32][132];
    __shared__ float sW[32][128];
    if ((int)blockIdx.x >= gemmGrid) {
        int e = ((int)blockIdx.x - gemmGrid) * 256 + threadIdx.x;
        if (e < E) atomicAdd(&deg[__builtin_nontemporal_load(ei + E + e)], 1);
        return;
    }
    const int tid = threadIdx.x;
    const int bm = blockIdx.x * 128;
    const int m0 = (tid >> 4) * 8;
    const int c4 = (tid & 15) * 4;
    const int xf = tid & 7;
    float acc[8][8] = {};
    for (int k0 = 0; k0 < 128; k0 += 32) {
        #pragma unroll
        for (int it = 0; it < 4; ++it) {
            int i = tid + it * 256;
            int row = bm + (i >> 3);
            int rc = min(row, N - 1);
            float4 v = *(const float4*)(X + (size_t)rc * 128 + k0 + xf * 4);
            int m = i >> 3;
            sX[xf * 4 + 0][m] = v.x;
            sX[xf * 4 + 1][m] = v.y;
            sX[xf * 4 + 2][m] = v.z;
            sX[xf * 4 + 3][m] = v.w;
        }
        #pragma unroll
        for (int it = 0; it < 4; ++it) {
            int i = tid + it * 256;
            int wr = i >> 5;
            int wf = i & 31;
            *(float4*)(&sW[wr][wf * 4]) =
                *(const float4*)(W + (size_t)(k0 + wr) * 128 + wf * 4);
        }
        __syncthreads();
        #pragma unroll
        for (int kk = 0; kk < 32; ++kk) {
            float4 a0 = *(const float4*)(&sX[kk][m0]);
            float4 a1 = *(const float4*)(&sX[kk][m0 + 4]);
            float4 b0 = *(const float4*)(&sW[kk][c4]);
            float4 b1 = *(const float4*)(&sW[kk][64 + c4]);
            float av[8] = {a0.x, a0.y, a0.z, a0.w, a1.x, a1.y, a1.z, a1.w};
            float bv[8] = {b0.x, b0.y, b0.z, b0.w, b1.x, b1.y, b1.z, b1.w};
            #pragma unroll
            for (int r = 0; r < 8; ++r)
                #pragma unroll
                for (int c = 0; c < 8; ++c)
                    acc[r][c] = fmaf(av[r], bv[c], acc[r][c]);
        }
        __syncthreads();
    }
    #pragma unroll
    for (int r = 0; r < 8; ++r) {
        int row = bm + m0 + r;
        if (row < N) {
            ushort4 o0 = {f2bf_rne(acc[r][0]), f2bf_rne(acc[r][1]),
                          f2bf_rne(acc[r][2]), f2bf_rne(acc[r][3])};
            ushort4 o1 = {f2bf_rne(acc[r][4]), f2bf_rne(acc[r][5]),
                          f2bf_rne(acc[r][6]), f2bf_rne(acc[r][7])};
            *(ushort4*)(Y + (size_t)row * 128 + c4)      = o0;
            *(ushort4*)(Y + (size_t)row * 128 + 64 + c4) = o1;
        }
    }
}

// ---- Ybf16[N,128] = X[N,128] @ W[128,128].  BM=128, BK=32; 8x8 microtile.
__global__ __launch_bounds__(256) void k_gemm128(const float* __restrict__ X,
                                                 const float* __restrict__ W,
                                                 ushort_t* __restrict__ Y, int N) {
    __shared__ float sX[32][132];
    __shared__ float sW[32][128];
    const int tid = threadIdx.x;
    const int bm = blockIdx.x * 128;
    const int m0 = (tid >> 4) * 8;
    const int c4 = (tid & 15) * 4;
    const int xf = tid & 7;
    float acc[8][8] = {};
    for (int k0 = 0; k0 < 128; k0 += 32) {
        #pragma unroll
        for (int it = 0; it < 4; ++it) {
            int i = tid + it * 256;
            int row = bm + (i >> 3);
            int rc = min(row, N - 1);
            float4 v = *(const float4*)(X + (size_t)rc * 128 + k0 + xf * 4);
            int m = i >> 3;
            sX[xf * 4 + 0][m] = v.x;
            sX[xf * 4 + 1][m] = v.y;
            sX[xf * 4 + 2][m] = v.z;
            sX[xf * 4 + 3][m] = v.w;
        }
        #pragma unroll
        for (int it = 0; it < 4; ++it) {
            int i = tid + it * 256;
            int wr = i >> 5;
            int wf = i & 31;
            *(float4*)(&sW[wr][wf * 4]) =
                *(const float4*)(W + (size_t)(k0 + wr) * 128 + wf * 4);
        }
        __syncthreads();
        #pragma unroll
        for (int kk = 0; kk < 32; ++kk) {
            float4 a0 = *(const float4*)(&sX[kk][m0]);
            float4 a1 = *(const float4*)(&sX[kk][m0 + 4]);
            float4 b0 = *(const float4*)(&sW[kk][c4]);
            float4 b1 = *(const float4*)(&sW[kk][64 + c4]);
            float av[8] = {a0.x, a0.y, a0.z, a0.w, a1.x, a1.y, a1.z, a1.w};
            float bv[8] = {b0.x, b0.y, b0.z, b0.w, b1.x, b1.y, b1.z, b1.w};
            #pragma unroll
            for (int r = 0; r < 8; ++r)
                #pragma unroll
                for (int c = 0; c < 8; ++c)
                    acc[r][c] = fmaf(av[r], bv[c], acc[r][c]);
        }
        __syncthreads();
    }
    #pragma unroll
    for (int r = 0; r < 8; ++r) {
        int row = bm + m0 + r;
        if (row < N) {
            ushort4 o0 = {f2bf_rne(acc[r][0]), f2bf_rne(acc[r][1]),
                          f2bf_rne(acc[r][2]), f2bf_rne(acc[r][3])};
            ushort4 o1 = {f2bf_rne(acc[r][4]), f2bf_rne(acc[r][5]),
                          f2bf_rne(acc[r][6]), f2bf_rne(acc[r][7])};
            *(ushort4*)(Y + (size_t)row * 128 + c4)      = o0;
            *(ushort4*)(Y + (size_t)row * 128 + 64 + c4) = o1;
        }
    }
}

// ---- Ybf16[N,40 (stride 64)] = X[N,128] @ W[128,40].  BM=128, BK=32. ----
__global__ __launch_bounds__(256) void k_gemm40(const float* __restrict__ X,
                                                const float* __restrict__ W,
                                                ushort_t* __restrict__ Y, int N) {
    __shared__ float sX[32][132];
    __shared__ float sW[32][40];
    const int tid = threadIdx.x;
    const int bm = blockIdx.x * 128;
    const int m0 = (tid >> 3) * 4;
    const int n0 = (tid & 7) * 5;
    const int xf = tid & 7;
    float acc[4][5] = {};
    for (int k0 = 0; k0 < 128; k0 += 32) {
        #pragma unroll
        for (int it = 0; it < 4; ++it) {
            int i = tid + it * 256;
            int row = bm + (i >> 3);
            int rc = min(row, N - 1);
            float4 v = *(const float4*)(X + (size_t)rc * 128 + k0 + xf * 4);
            int m = i >> 3;
            sX[xf * 4 + 0][m] = v.x;
            sX[xf * 4 + 1][m] = v.y;
            sX[xf * 4 + 2][m] = v.z;
            sX[xf * 4 + 3][m] = v.w;
        }
        for (int i = tid; i < 320; i += 256) {
            int wr = i / 10;
            int wf = i - wr * 10;
            *(float4*)(&sW[wr][wf * 4]) =
                *(const float4*)(W + (size_t)(k0 + wr) * 40 + wf * 4);
        }
        __syncthreads();
        #pragma unroll
        for (int kk = 0; kk < 32; ++kk) {
            float4 a = *(const float4*)(&sX[kk][m0]);
            float av[4] = {a.x, a.y, a.z, a.w};
            #pragma unroll
            for (int c = 0; c < 5; ++c) {
                float b = sW[kk][n0 + c];
                #pragma unroll
                for (int r = 0; r < 4; ++r)
                    acc[r][c] = fmaf(av[r], b, acc[r][c]);
            }
        }
        __syncthreads();
    }
    #pragma unroll
    for (int r = 0; r < 4; ++r) {
        int row = bm + m0 + r;
        if (row < N) {
            #pragma unroll
            for (int c = 0; c < 5; ++c)
                Y[(size_t)row * 64 + n0 + c] = f2bf_rne(acc[r][c]);
        }
    }
}

// Uniform full-wave agg, F=128 bf16; src-only csr, weight recomputed.
template <bool RELU>
__global__ __launch_bounds__(256) void k_agg128(
        const ushort_t* __restrict__ XW, const int* __restrict__ rowptr,
        const int* __restrict__ csr, const float* __restrict__ dinv,
        const float* __restrict__ bias, float* __restrict__ out, int n) {
    const int lane = threadIdx.x & 63;
    const int wv = __builtin_amdgcn_readfirstlane(threadIdx.x >> 6);
    const int d = blockIdx.x * 4 + wv;
    if (d >= n) return;
    const uint_t* xw = (const uint_t*)XW;           // row stride 64 uints (256 B)
    float dv = dinv[d];
    float w0 = dv * dv;
    uint_t sq = xw[(size_t)d * 64 + lane];
    float2 a;
    a.x = w0 * bflo(sq);
    a.y = w0 * bfhi(sq);
    int j = rowptr[d], end = rowptr[d + 1];
    for (; j + 8 <= end; j += 8) {
        int s0 = __builtin_nontemporal_load(csr + j + 0);
        int s1 = __builtin_nontemporal_load(csr + j + 1);
        int s2 = __builtin_nontemporal_load(csr + j + 2);
        int s3 = __builtin_nontemporal_load(csr + j + 3);
        int s4 = __builtin_nontemporal_load(csr + j + 4);
        int s5 = __builtin_nontemporal_load(csr + j + 5);
        int s6 = __builtin_nontemporal_load(csr + j + 6);
        int s7 = __builtin_nontemporal_load(csr + j + 7);
        uint_t u0 = xw[(size_t)s0 * 64 + lane];
        uint_t u1 = xw[(size_t)s1 * 64 + lane];
        uint_t u2 = xw[(size_t)s2 * 64 + lane];
        uint_t u3 = xw[(size_t)s3 * 64 + lane];
        uint_t u4 = xw[(size_t)s4 * 64 + lane];
        uint_t u5 = xw[(size_t)s5 * 64 + lane];
        uint_t u6 = xw[(size_t)s6 * 64 + lane];
        uint_t u7 = xw[(size_t)s7 * 64 + lane];
        float w0e = dinv[s0] * dv, w1e = dinv[s1] * dv;
        float w2e = dinv[s2] * dv, w3e = dinv[s3] * dv;
        float w4e = dinv[s4] * dv, w5e = dinv[s5] * dv;
        float w6e = dinv[s6] * dv, w7e = dinv[s7] * dv;
        a.x = fmaf(w0e, bflo(u0), a.x); a.y = fmaf(w0e, bfhi(u0), a.y);
        a.x = fmaf(w1e, bflo(u1), a.x); a.y = fmaf(w1e, bfhi(u1), a.y);
        a.x = fmaf(w2e, bflo(u2), a.x); a.y = fmaf(w2e, bfhi(u2), a.y);
        a.x = fmaf(w3e, bflo(u3), a.x); a.y = fmaf(w3e, bfhi(u3), a.y);
        a.x = fmaf(w4e, bflo(u4), a.x); a.y = fmaf(w4e, bfhi(u4), a.y);
        a.x = fmaf(w5e, bflo(u5), a.x); a.y = fmaf(w5e, bfhi(u5), a.y);
        a.x = fmaf(w6e, bflo(u6), a.x); a.y = fmaf(w6e, bfhi(u6), a.y);
        a.x = fmaf(w7e, bflo(u7), a.x); a.y = fmaf(w7e, bfhi(u7), a.y);
    }
    for (; j < end; ++j) {
        int s = __builtin_nontemporal_load(csr + j);
        float we = dinv[s] * dv;
        uint_t u = xw[(size_t)s * 64 + lane];
        a.x = fmaf(we, bflo(u), a.x);
        a.y = fmaf(we, bfhi(u), a.y);
    }
    float2 b = ((const float2*)bias)[lane];
    a.x += b.x; a.y += b.y;
    if (RELU) {
        a.x = fmaxf(a.x, 0.f);
        a.y = fmaxf(a.y, 0.f);
    }
    ((float2*)out)[(size_t)d * 64 + lane] = a;
}

// Half-wave per dst, F=40 bf16 rows padded to stride 64; src-only csr.
__global__ __launch_bounds__(256) void k_agg40(
        const ushort_t* __restrict__ XW, const int* __restrict__ rowptr,
        const int* __restrict__ csr, const float* __restrict__ dinv,
        const float* __restrict__ bias, float* __restrict__ out, int n) {
    const int lane = threadIdx.x & 31;
    const int sub  = threadIdx.x >> 5;
    const int d = blockIdx.x * 8 + sub;
    if (d >= n || lane >= 20) return;
    const uint_t* xw = (const uint_t*)XW;       // row stride 32 uints
    float dv = dinv[d];
    float w0 = dv * dv;
    uint_t sq = xw[(size_t)d * 32 + lane];
    float2 a;
    a.x = w0 * bflo(sq);
    a.y = w0 * bfhi(sq);
    int j = rowptr[d], end = rowptr[d + 1];
    for (; j + 4 <= end; j += 4) {
        int s0 = __builtin_nontemporal_load(csr + j + 0);
        int s1 = __builtin_nontemporal_load(csr + j + 1);
        int s2 = __builtin_nontemporal_load(csr + j + 2);
        int s3 = __builtin_nontemporal_load(csr + j + 3);
        uint_t u0 = xw[(size_t)s0 * 32 + lane];
        uint_t u1 = xw[(size_t)s1 * 32 + lane];
        uint_t u2 = xw[(size_t)s2 * 32 + lane];
        uint_t u3 = xw[(size_t)s3 * 32 + lane];
        float w0e = dinv[s0] * dv, w1e = dinv[s1] * dv;
        float w2e = dinv[s2] * dv, w3e = dinv[s3] * dv;
        a.x = fmaf(w0e, bflo(u0), a.x); a.y = fmaf(w0e, bfhi(u0), a.y);
        a.x = fmaf(w1e, bflo(u1), a.x); a.y = fmaf(w1e, bfhi(u1), a.y);
        a.x = fmaf(w2e, bflo(u2), a.x); a.y = fmaf(w2e, bfhi(u2), a.y);
        a.x = fmaf(w3e, bflo(u3), a.x); a.y = fmaf(w3e, bfhi(u3), a.y);
    }
    for (; j < end; ++j) {
        int s = __builtin_nontemporal_load(csr + j);
        float we = dinv[s] * dv;
        uint_t u = xw[(size_t)s * 32 + lane];
        a.x = fmaf(we, bflo(u), a.x);
        a.y = fmaf(we, bfhi(u), a.y);
    }
    float2 b = ((const float2*)bias)[lane];
    a.x += b.x; a.y += b.y;
    ((float2*)out)[(size_t)d * 20 + lane] = a;
}

static inline int cdiv(long long a, int b) { return (int)((a + b - 1) / b); }

extern "C" void kernel_launch(void* const* d_in, const int* in_sizes, int n_in,
                              void* d_out, int out_size, void* d_ws, size_t ws_size,
                              hipStream_t stream) {
    const float* x  = (const float*)d_in[0];
    const int*   ei = (const int*)d_in[1];
    const float* W1 = (const float*)d_in[2];
    const float* b1 = (const float*)d_in[3];
    const float* W2 = (const float*)d_in[4];
    const float* b2 = (const float*)d_in[5];
    const float* W3 = (const float*)d_in[6];
    const float* b3 = (const float*)d_in[7];
    float* out = (float*)d_out;

    const int N = in_sizes[0] / 128;   // 50000
    const int E = in_sizes[1] / 2;     // 800000
    const int nb = cdiv(N, 256);       // 196 scan blocks (co-resident)

    char* ws = (char*)d_ws;
    int*   deg    = (int*)ws;                 ws += (size_t)N * 4;
    unsigned long long* partials = (unsigned long long*)ws;
                                              ws += (size_t)nb * 8;
    int*   rowptr = (int*)ws;                 ws += (size_t)(N + 1) * 4;
    int*   cursor = (int*)ws;                 ws += (size_t)N * 4;
    float* dinv   = (float*)ws;               ws += (size_t)N * 4;
    ws = (char*)(((uintptr_t)ws + 127) & ~(uintptr_t)127);
    int*   csr    = (int*)ws;                 ws += (size_t)E * 4;
    ws = (char*)(((uintptr_t)ws + 127) & ~(uintptr_t)127);
    char*  bufA   = ws;                       ws += (size_t)N * 128 * 4;
    float* bufB   = (float*)ws;

    const int BT = 256;
    const int gemmGrid = cdiv(N, 128);          // 391
    const int degGrid  = cdiv(E, BT);           // 3125

    // memset covers deg AND partials (contiguous).
    hipMemsetAsync(deg, 0, (size_t)N * 4 + (size_t)nb * 8, stream);

    // layer-1 GEMM ∪ degree count (independent work, one dispatch)
    k_l1<<<gemmGrid + degGrid, 256, 0, stream>>>(x, W1, (ushort_t*)bufA, N,
                                                 ei, deg, E, gemmGrid);
    // CSR build
    k_scan<<<nb, 256, 0, stream>>>(deg, partials, rowptr, cursor, dinv, N);
    k_fill<<<cdiv(E, BT * 4) * 8, 256, 0, stream>>>(ei, cursor, csr, E, N);

    // layer 1 aggregation
    k_agg128<true><<<cdiv(N, 4), 256, 0, stream>>>((const ushort_t*)bufA, rowptr, csr, dinv, b1, bufB, N);
    // layer 2
    k_gemm128<<<cdiv(N, 128), 256, 0, stream>>>(bufB, W2, (ushort_t*)bufA, N);
    k_agg128<true><<<cdiv(N, 4), 256, 0, stream>>>((const ushort_t*)bufA, rowptr, csr, dinv, b2, bufB, N);
    // layer 3
    k_gemm40<<<cdiv(N, 128), 256, 0, stream>>>(bufB, W3, (ushort_t*)bufA, N);
    k_agg40<<<cdiv(N, 8), 256, 0, stream>>>((const ushort_t*)bufA, rowptr, csr, dinv, b3, out, N);
}

// Round 6
// 285.763 us; speedup vs baseline: 3.5584x; 1.0932x over previous
//
#include <hip/hip_runtime.h>

typedef unsigned short ushort_t;
typedef unsigned int uint_t;
typedef short bf16x8 __attribute__((ext_vector_type(8)));
typedef float f32x4 __attribute__((ext_vector_type(4)));

// ---------------------------------------------------------------------------
// GCN 3-layer forward.  N=50000, E=800000, D=H=128, C=40.
// Round 23: (a) revert aggs/fill to R17 packed int2 csr (R22's dinv[s]
// reload was a second dependent VMEM op on the gather chain: -11us);
// (b) all three GEMMs -> MFMA 16x16x32 bf16.  K=128 fits one LDS staging
// pass: sA[64][136] + sBt[cols][136] staged, one barrier, 128 MFMA/block,
// no K-loop.  Weights pre-transposed to bf16 once by k_prep.  Agg outputs
// switch to bf16 (GEMM would round them anyway) halving agg-write/GEMM-read.
// C/D layout (m89-verified): col=lane&15, row=(lane>>4)*4+reg.
// A: lane holds A[row=lane&15][k=(lane>>4)*8+e]; B: B[k=(lane>>4)*8+e][col=lane&15].
// Chain: prep -> memset -> l1(mfma ∪ deg) -> scan -> fill -> agg128 ->
//        gemm128 -> agg128 -> gemm40 -> agg40.
// ws: [deg][partials][rowptr][cursor][dinv][csr int2][W1t][W2t][W3t]
//     [bufA N*128 bf16][bufB N*128 bf16][bufD N*64 bf16]
// ---------------------------------------------------------------------------

__device__ __forceinline__ ushort_t f2bf_rne(float f) {
    uint_t u = __float_as_uint(f);
    u += 0x7fffu + ((u >> 16) & 1u);
    return (ushort_t)(u >> 16);
}
__device__ __forceinline__ float bflo(uint_t u) {
    return __uint_as_float(u << 16);
}
__device__ __forceinline__ float bfhi(uint_t u) {
    return __uint_as_float(u & 0xffff0000u);
}
__device__ __forceinline__ int2 ldnt2(const int2* p) {
    long long v = __builtin_nontemporal_load((const long long*)p);
    int2 r;
    r.x = (int)(v & 0xffffffffll);
    r.y = (int)(v >> 32);
    return r;
}

// ---- weight prep: Wt[n][k] = bf16(W[k][n]); W3t rows 40..47 zeroed. ----
__global__ __launch_bounds__(256) void k_prep(const float* __restrict__ W1,
                                              const float* __restrict__ W2,
                                              const float* __restrict__ W3,
                                              ushort_t* __restrict__ W1t,
                                              ushort_t* __restrict__ W2t,
                                              ushort_t* __restrict__ W3t) {
    int idx = blockIdx.x * 256 + threadIdx.x;
    if (idx < 16384) {
        int n = idx >> 7, k = idx & 127;
        W1t[idx] = f2bf_rne(W1[k * 128 + n]);
    } else if (idx < 32768) {
        int j = idx - 16384;
        int n = j >> 7, k = j & 127;
        W2t[j] = f2bf_rne(W2[k * 128 + n]);
    } else if (idx < 38912) {
        int j = idx - 32768;
        int n = j >> 7, k = j & 127;
        W3t[j] = (n < 40) ? f2bf_rne(W3[k * 40 + n]) : (ushort_t)0;
    }
}

// Single-dispatch scan, wave-parallel decoupled lookback (R16).
__global__ __launch_bounds__(256) void k_scan(
        const int* __restrict__ deg, unsigned long long* __restrict__ partials,
        int* __restrict__ rowptr, int* __restrict__ cursor,
        float* __restrict__ dinv, int n) {
    __shared__ int s[256];
    __shared__ int sprefix;
    const int b = blockIdx.x, t = threadIdx.x;
    const int i = b * 256 + t;
    int v = (i < n) ? deg[i] : 0;
    s[t] = v;
    __syncthreads();
    for (int off = 1; off < 256; off <<= 1) {
        int u = (t >= off) ? s[t - off] : 0;
        __syncthreads();
        s[t] += u;
        __syncthreads();
    }
    if (t == 0) {
        __hip_atomic_store(&partials[b],
                ((unsigned long long)s[255] << 2) | 1ull,
                __ATOMIC_RELEASE, __HIP_MEMORY_SCOPE_AGENT);
        if (b == 0) {
            __hip_atomic_store(&partials[0],
                    ((unsigned long long)s[255] << 2) | 2ull,
                    __ATOMIC_RELEASE, __HIP_MEMORY_SCOPE_AGENT);
            sprefix = 0;
        }
    }
    if (b > 0 && t < 64) {
        int acc = 0;
        int k = b - 1;
        for (;;) {
            int idx = k - t;
            unsigned long long p;
            unsigned st;
            do {
                if (idx >= 0) {
                    p = __hip_atomic_load(&partials[idx],
                            __ATOMIC_ACQUIRE, __HIP_MEMORY_SCOPE_AGENT);
                } else {
                    p = 2ull;
                }
                st = (unsigned)(p & 3ull);
            } while (st == 0);
            unsigned long long bal = __ballot(st == 2);
            int L = (bal != 0) ? (__ffsll((unsigned long long)bal) - 1) : 64;
            int val = (int)(p >> 2);
            int contrib = (t <= L) ? val : 0;
            #pragma unroll
            for (int o = 32; o > 0; o >>= 1) contrib += __shfl_down(contrib, o);
            if (t == 0) acc += contrib;
            if (L < 64) break;
            k -= 64;
        }
        if (t == 0) {
            __hip_atomic_store(&partials[b],
                    (((unsigned long long)(acc + s[255])) << 2) | 2ull,
                    __ATOMIC_RELEASE, __HIP_MEMORY_SCOPE_AGENT);
            sprefix = acc;
        }
    }
    __syncthreads();
    if (i < n) {
        int ex = sprefix + s[t] - v;
        rowptr[i] = ex;
        cursor[i] = ex;
        dinv[i] = rsqrtf((float)(v + 1));
        if (i == n - 1) rowptr[n] = ex + v;
    }
}

// XCD-partitioned scatter (R12/R17 form: packed int2 csr).
__global__ __launch_bounds__(256) void k_fill(const int* __restrict__ ei,
                                              int* __restrict__ cursor,
                                              const float* __restrict__ dinv,
                                              int2* __restrict__ csr, int E, int n) {
    const int xcd = blockIdx.x & 7;
    const int e = (blockIdx.x >> 3) * 256 + threadIdx.x;
    if (e >= E) return;
    int d = __builtin_nontemporal_load(ei + E + e);
    const int lo = (int)(((long long)xcd * n) >> 3);
    const int hi = (int)(((long long)(xcd + 1) * n) >> 3);
    if (d < lo || d >= hi) return;
    int s = __builtin_nontemporal_load(ei + e);
    int pos = atomicAdd(&cursor[d], 1);
    int2 p;
    p.x = s;
    p.y = __float_as_int(dinv[s] * dinv[d]);
    csr[pos] = p;
}

// ---- UNION: blocks [0,gemmGrid) = MFMA gemm Ybf16[N,128]=bf16(X)@W1t;
//      blocks >= gemmGrid do deg count.  BM=64, one K=128 staging pass.
__global__ __launch_bounds__(256) void k_l1(const float* __restrict__ X,
                                            const ushort_t* __restrict__ W1t,
                                            ushort_t* __restrict__ Y, int N,
                                            const int* __restrict__ ei,
                                            int* __restrict__ deg, int E,
                                            int gemmGrid) {
    __shared__ ushort_t sA[64][136];
    __shared__ ushort_t sB[128][136];
    if ((int)blockIdx.x >= gemmGrid) {
        int e = ((int)blockIdx.x - gemmGrid) * 256 + threadIdx.x;
        if (e < E) atomicAdd(&deg[__builtin_nontemporal_load(ei + E + e)], 1);
        return;
    }
    const int tid = threadIdx.x;
    const int bm = blockIdx.x * 64;
    // stage A: fp32 -> bf16, 64 rows x 32 float4-chunks
    #pragma unroll
    for (int it = 0; it < 8; ++it) {
        int i = tid + it * 256;          // 0..2047
        int row = i >> 5;
        int c4 = i & 31;
        int rc = min(bm + row, N - 1);
        float4 v = *(const float4*)(X + (size_t)rc * 128 + c4 * 4);
        ushort4 o = {f2bf_rne(v.x), f2bf_rne(v.y), f2bf_rne(v.z), f2bf_rne(v.w)};
        *(ushort4*)(&sA[row][c4 * 4]) = o;
    }
    // stage B: W1t bf16 [128][128], 16B chunks
    #pragma unroll
    for (int it = 0; it < 8; ++it) {
        int i = tid + it * 256;          // 0..2047
        int row = i >> 4;
        int c8 = i & 15;
        *(bf16x8*)(&sB[row][c8 * 8]) =
            *(const bf16x8*)(W1t + (size_t)row * 128 + c8 * 8);
    }
    __syncthreads();
    const int lane = tid & 63;
    const int wv = tid >> 6;
    const int m0 = wv * 16;
    const int lr = lane & 15;
    const int lg = lane >> 4;
    bf16x8 afr[4];
    #pragma unroll
    for (int kk = 0; kk < 4; ++kk)
        afr[kk] = *(const bf16x8*)(&sA[m0 + lr][kk * 32 + lg * 8]);
    f32x4 acc[8];
    #pragma unroll
    for (int ct = 0; ct < 8; ++ct) {
        acc[ct] = (f32x4){0.f, 0.f, 0.f, 0.f};
        #pragma unroll
        for (int kk = 0; kk < 4; ++kk) {
            bf16x8 bfr = *(const bf16x8*)(&sB[ct * 16 + lr][kk * 32 + lg * 8]);
            acc[ct] = __builtin_amdgcn_mfma_f32_16x16x32_bf16(afr[kk], bfr,
                                                              acc[ct], 0, 0, 0);
        }
    }
    #pragma unroll
    for (int i = 0; i < 4; ++i) {
        int row = bm + m0 + lg * 4 + i;
        if (row < N) {
            #pragma unroll
            for (int ct = 0; ct < 8; ++ct)
                Y[(size_t)row * 128 + ct * 16 + lr] = f2bf_rne(acc[ct][i]);
        }
    }
}

// ---- MFMA: Ybf16[N,128] = Xbf16[N,128] @ W2t.  BM=64, K=128 one pass. ----
__global__ __launch_bounds__(256) void k_gemm128(const ushort_t* __restrict__ Xb,
                                                 const ushort_t* __restrict__ Wt,
                                                 ushort_t* __restrict__ Y, int N) {
    __shared__ ushort_t sA[64][136];
    __shared__ ushort_t sB[128][136];
    const int tid = threadIdx.x;
    const int bm = blockIdx.x * 64;
    #pragma unroll
    for (int it = 0; it < 4; ++it) {
        int i = tid + it * 256;          // 0..1023 (64 rows x 16 chunks)
        int row = i >> 4;
        int c8 = i & 15;
        int rc = min(bm + row, N - 1);
        *(bf16x8*)(&sA[row][c8 * 8]) =
            *(const bf16x8*)(Xb + (size_t)rc * 128 + c8 * 8);
    }
    #pragma unroll
    for (int it = 0; it < 8; ++it) {
        int i = tid + it * 256;
        int row = i >> 4;
        int c8 = i & 15;
        *(bf16x8*)(&sB[row][c8 * 8]) =
            *(const bf16x8*)(Wt + (size_t)row * 128 + c8 * 8);
    }
    __syncthreads();
    const int lane = tid & 63;
    const int wv = tid >> 6;
    const int m0 = wv * 16;
    const int lr = lane & 15;
    const int lg = lane >> 4;
    bf16x8 afr[4];
    #pragma unroll
    for (int kk = 0; kk < 4; ++kk)
        afr[kk] = *(const bf16x8*)(&sA[m0 + lr][kk * 32 + lg * 8]);
    f32x4 acc[8];
    #pragma unroll
    for (int ct = 0; ct < 8; ++ct) {
        acc[ct] = (f32x4){0.f, 0.f, 0.f, 0.f};
        #pragma unroll
        for (int kk = 0; kk < 4; ++kk) {
            bf16x8 bfr = *(const bf16x8*)(&sB[ct * 16 + lr][kk * 32 + lg * 8]);
            acc[ct] = __builtin_amdgcn_mfma_f32_16x16x32_bf16(afr[kk], bfr,
                                                              acc[ct], 0, 0, 0);
        }
    }
    #pragma unroll
    for (int i = 0; i < 4; ++i) {
        int row = bm + m0 + lg * 4 + i;
        if (row < N) {
            #pragma unroll
            for (int ct = 0; ct < 8; ++ct)
                Y[(size_t)row * 128 + ct * 16 + lr] = f2bf_rne(acc[ct][i]);
        }
    }
}

// ---- MFMA: Ybf16[N,40(stride 64)] = Xbf16[N,128] @ W3t[48][128]. ----
__global__ __launch_bounds__(256) void k_gemm40(const ushort_t* __restrict__ Xb,
                                                const ushort_t* __restrict__ Wt,
                                                ushort_t* __restrict__ Y, int N) {
    __shared__ ushort_t sA[64][136];
    __shared__ ushort_t sB[48][136];
    const int tid = threadIdx.x;
    const int bm = blockIdx.x * 64;
    #pragma unroll
    for (int it = 0; it < 4; ++it) {
        int i = tid + it * 256;
        int row = i >> 4;
        int c8 = i & 15;
        int rc = min(bm + row, N - 1);
        *(bf16x8*)(&sA[row][c8 * 8]) =
            *(const bf16x8*)(Xb + (size_t)rc * 128 + c8 * 8);
    }
    #pragma unroll
    for (int it = 0; it < 3; ++it) {
        int i = tid + it * 256;          // 0..767 (48 rows x 16 chunks)
        int row = i >> 4;
        int c8 = i & 15;
        *(bf16x8*)(&sB[row][c8 * 8]) =
            *(const bf16x8*)(Wt + (size_t)row * 128 + c8 * 8);
    }
    __syncthreads();
    const int lane = tid & 63;
    const int wv = tid >> 6;
    const int m0 = wv * 16;
    const int lr = lane & 15;
    const int lg = lane >> 4;
    bf16x8 afr[4];
    #pragma unroll
    for (int kk = 0; kk < 4; ++kk)
        afr[kk] = *(const bf16x8*)(&sA[m0 + lr][kk * 32 + lg * 8]);
    f32x4 acc[3];
    #pragma unroll
    for (int ct = 0; ct < 3; ++ct) {
        acc[ct] = (f32x4){0.f, 0.f, 0.f, 0.f};
        #pragma unroll
        for (int kk = 0; kk < 4; ++kk) {
            bf16x8 bfr = *(const bf16x8*)(&sB[ct * 16 + lr][kk * 32 + lg * 8]);
            acc[ct] = __builtin_amdgcn_mfma_f32_16x16x32_bf16(afr[kk], bfr,
                                                              acc[ct], 0, 0, 0);
        }
    }
    #pragma unroll
    for (int i = 0; i < 4; ++i) {
        int row = bm + m0 + lg * 4 + i;
        if (row < N) {
            #pragma unroll
            for (int ct = 0; ct < 3; ++ct) {
                int col = ct * 16 + lr;
                if (col < 40)
                    Y[(size_t)row * 64 + col] = f2bf_rne(acc[ct][i]);
            }
        }
    }
}

// Uniform full-wave agg, F=128 bf16 in -> bf16 out (R17 form + bf16 store).
template <bool RELU>
__global__ __launch_bounds__(256) void k_agg128(
        const ushort_t* __restrict__ XW, const int* __restrict__ rowptr,
        const int2* __restrict__ csr, const float* __restrict__ dinv,
        const float* __restrict__ bias, ushort_t* __restrict__ out, int n) {
    const int lane = threadIdx.x & 63;
    const int wv = __builtin_amdgcn_readfirstlane(threadIdx.x >> 6);
    const int d = blockIdx.x * 4 + wv;
    if (d >= n) return;
    const uint_t* xw = (const uint_t*)XW;           // row stride 64 uints (256 B)
    float dv = dinv[d];
    float w0 = dv * dv;
    uint_t sq = xw[(size_t)d * 64 + lane];
    float2 a;
    a.x = w0 * bflo(sq);
    a.y = w0 * bfhi(sq);
    int j = rowptr[d], end = rowptr[d + 1];
    for (; j + 8 <= end; j += 8) {
        int2 p0 = ldnt2(csr + j + 0), p1 = ldnt2(csr + j + 1);
        int2 p2 = ldnt2(csr + j + 2), p3 = ldnt2(csr + j + 3);
        int2 p4 = ldnt2(csr + j + 4), p5 = ldnt2(csr + j + 5);
        int2 p6 = ldnt2(csr + j + 6), p7 = ldnt2(csr + j + 7);
        uint_t u0 = xw[(size_t)p0.x * 64 + lane];
        uint_t u1 = xw[(size_t)p1.x * 64 + lane];
        uint_t u2 = xw[(size_t)p2.x * 64 + lane];
        uint_t u3 = xw[(size_t)p3.x * 64 + lane];
        uint_t u4 = xw[(size_t)p4.x * 64 + lane];
        uint_t u5 = xw[(size_t)p5.x * 64 + lane];
        uint_t u6 = xw[(size_t)p6.x * 64 + lane];
        uint_t u7 = xw[(size_t)p7.x * 64 + lane];
        float w0e = __int_as_float(p0.y), w1e = __int_as_float(p1.y);
        float w2e = __int_as_float(p2.y), w3e = __int_as_float(p3.y);
        float w4e = __int_as_float(p4.y), w5e = __int_as_float(p5.y);
        float w6e = __int_as_float(p6.y), w7e = __int_as_float(p7.y);
        a.x = fmaf(w0e, bflo(u0), a.x); a.y = fmaf(w0e, bfhi(u0), a.y);
        a.x = fmaf(w1e, bflo(u1), a.x); a.y = fmaf(w1e, bfhi(u1), a.y);
        a.x = fmaf(w2e, bflo(u2), a.x); a.y = fmaf(w2e, bfhi(u2), a.y);
        a.x = fmaf(w3e, bflo(u3), a.x); a.y = fmaf(w3e, bfhi(u3), a.y);
        a.x = fmaf(w4e, bflo(u4), a.x); a.y = fmaf(w4e, bfhi(u4), a.y);
        a.x = fmaf(w5e, bflo(u5), a.x); a.y = fmaf(w5e, bfhi(u5), a.y);
        a.x = fmaf(w6e, bflo(u6), a.x); a.y = fmaf(w6e, bfhi(u6), a.y);
        a.x = fmaf(w7e, bflo(u7), a.x); a.y = fmaf(w7e, bfhi(u7), a.y);
    }
    for (; j < end; ++j) {
        int2 p = ldnt2(csr + j);
        float we = __int_as_float(p.y);
        uint_t u = xw[(size_t)p.x * 64 + lane];
        a.x = fmaf(we, bflo(u), a.x);
        a.y = fmaf(we, bfhi(u), a.y);
    }
    float2 b = ((const float2*)bias)[lane];
    a.x += b.x; a.y += b.y;
    if (RELU) {
        a.x = fmaxf(a.x, 0.f);
        a.y = fmaxf(a.y, 0.f);
    }
    uint_t pack = (uint_t)f2bf_rne(a.x) | ((uint_t)f2bf_rne(a.y) << 16);
    ((uint_t*)out)[(size_t)d * 64 + lane] = pack;
}

// Half-wave per dst, F=40 bf16 rows padded to stride 64 -> fp32 out (R17).
__global__ __launch_bounds__(256) void k_agg40(
        const ushort_t* __restrict__ XW, const int* __restrict__ rowptr,
        const int2* __restrict__ csr, const float* __restrict__ dinv,
        const float* __restrict__ bias, float* __restrict__ out, int n) {
    const int lane = threadIdx.x & 31;
    const int sub  = threadIdx.x >> 5;
    const int d = blockIdx.x * 8 + sub;
    if (d >= n || lane >= 20) return;
    const uint_t* xw = (const uint_t*)XW;       // row stride 32 uints
    float dv = dinv[d];
    float w0 = dv * dv;
    uint_t sq = xw[(size_t)d * 32 + lane];
    float2 a;
    a.x = w0 * bflo(sq);
    a.y = w0 * bfhi(sq);
    int j = rowptr[d], end = rowptr[d + 1];
    for (; j + 4 <= end; j += 4) {
        int2 p0 = ldnt2(csr + j + 0), p1 = ldnt2(csr + j + 1);
        int2 p2 = ldnt2(csr + j + 2), p3 = ldnt2(csr + j + 3);
        uint_t u0 = xw[(size_t)p0.x * 32 + lane];
        uint_t u1 = xw[(size_t)p1.x * 32 + lane];
        uint_t u2 = xw[(size_t)p2.x * 32 + lane];
        uint_t u3 = xw[(size_t)p3.x * 32 + lane];
        float w0e = __int_as_float(p0.y), w1e = __int_as_float(p1.y);
        float w2e = __int_as_float(p2.y), w3e = __int_as_float(p3.y);
        a.x = fmaf(w0e, bflo(u0), a.x); a.y = fmaf(w0e, bfhi(u0), a.y);
        a.x = fmaf(w1e, bflo(u1), a.x); a.y = fmaf(w1e, bfhi(u1), a.y);
        a.x = fmaf(w2e, bflo(u2), a.x); a.y = fmaf(w2e, bfhi(u2), a.y);
        a.x = fmaf(w3e, bflo(u3), a.x); a.y = fmaf(w3e, bfhi(u3), a.y);
    }
    for (; j < end; ++j) {
        int2 p = ldnt2(csr + j);
        float we = __int_as_float(p.y);
        uint_t u = xw[(size_t)p.x * 32 + lane];
        a.x = fmaf(we, bflo(u), a.x);
        a.y = fmaf(we, bfhi(u), a.y);
    }
    float2 b = ((const float2*)bias)[lane];
    a.x += b.x; a.y += b.y;
    ((float2*)out)[(size_t)d * 20 + lane] = a;
}

static inline int cdiv(long long a, int b) { return (int)((a + b - 1) / b); }

extern "C" void kernel_launch(void* const* d_in, const int* in_sizes, int n_in,
                              void* d_out, int out_size, void* d_ws, size_t ws_size,
                              hipStream_t stream) {
    const float* x  = (const float*)d_in[0];
    const int*   ei = (const int*)d_in[1];
    const float* W1 = (const float*)d_in[2];
    const float* b1 = (const float*)d_in[3];
    const float* W2 = (const float*)d_in[4];
    const float* b2 = (const float*)d_in[5];
    const float* W3 = (const float*)d_in[6];
    const float* b3 = (const float*)d_in[7];
    float* out = (float*)d_out;

    const int N = in_sizes[0] / 128;   // 50000
    const int E = in_sizes[1] / 2;     // 800000
    const int nb = cdiv(N, 256);       // 196 scan blocks (co-resident)

    char* ws = (char*)d_ws;
    int*   deg    = (int*)ws;                 ws += (size_t)N * 4;
    unsigned long long* partials = (unsigned long long*)ws;
                                              ws += (size_t)nb * 8;
    int*   rowptr = (int*)ws;                 ws += (size_t)(N + 1) * 4;
    int*   cursor = (int*)ws;                 ws += (size_t)N * 4;
    float* dinv   = (float*)ws;               ws += (size_t)N * 4;
    ws = (char*)(((uintptr_t)ws + 127) & ~(uintptr_t)127);
    int2*     csr  = (int2*)ws;               ws += (size_t)E * 8;
    ushort_t* W1t  = (ushort_t*)ws;           ws += (size_t)16384 * 2;
    ushort_t* W2t  = (ushort_t*)ws;           ws += (size_t)16384 * 2;
    ushort_t* W3t  = (ushort_t*)ws;           ws += (size_t)6144 * 2;
    ws = (char*)(((uintptr_t)ws + 127) & ~(uintptr_t)127);
    ushort_t* bufA = (ushort_t*)ws;           ws += (size_t)N * 128 * 2;
    ushort_t* bufB = (ushort_t*)ws;           ws += (size_t)N * 128 * 2;
    ushort_t* bufD = (ushort_t*)ws;

    const int BT = 256;
    const int gemmGrid = cdiv(N, 64);           // 782
    const int degGrid  = cdiv(E, BT);           // 3125

    // weight transpose+cast (tiny) and deg/partials clear
    k_prep<<<cdiv(38912, 256), 256, 0, stream>>>(W1, W2, W3, W1t, W2t, W3t);
    hipMemsetAsync(deg, 0, (size_t)N * 4 + (size_t)nb * 8, stream);

    // layer-1 MFMA GEMM ∪ degree count
    k_l1<<<gemmGrid + degGrid, 256, 0, stream>>>(x, W1t, bufA, N,
                                                 ei, deg, E, gemmGrid);
    // CSR build
    k_scan<<<nb, 256, 0, stream>>>(deg, partials, rowptr, cursor, dinv, N);
    k_fill<<<cdiv(E, BT) * 8, 256, 0, stream>>>(ei, cursor, dinv, csr, E, N);

    // layer 1 aggregation -> bf16
    k_agg128<true><<<cdiv(N, 4), 256, 0, stream>>>(bufA, rowptr, csr, dinv, b1, bufB, N);
    // layer 2
    k_gemm128<<<cdiv(N, 64), 256, 0, stream>>>(bufB, W2t, bufA, N);
    k_agg128<true><<<cdiv(N, 4), 256, 0, stream>>>(bufA, rowptr, csr, dinv, b2, bufB, N);
    // layer 3
    k_gemm40<<<cdiv(N, 64), 256, 0, stream>>>(bufB, W3t, bufD, N);
    k_agg40<<<cdiv(N, 8), 256, 0, stream>>>(bufD, rowptr, csr, dinv, b3, out, N);
}